// Round 12
// baseline (53.465 us; speedup 1.0000x reference)
//
#include <hip/hip_runtime.h>
#include <hip/hip_bf16.h>
#include <stdint.h>

// Problem geometry
#define NB 64          // batch
#define NC 64          // C_IN
#define NU 2048        // N_UNITS
#define K_REAL 1296    // H*W = 36*36
#define K_PAD  1344    // 2 splits x 21 ks-steps of 32
#define M_ROWS 4096    // NB*NC
#define K_SPLIT 672

// GEMM tile
#define BM 256
#define BN 256

typedef __attribute__((ext_vector_type(4))) float f32x4;
typedef __attribute__((ext_vector_type(8))) short bf16x8;

__device__ __forceinline__ unsigned short f2bf_rne(float f) {
  union { float f; uint32_t u; } v; v.f = f;
  uint32_t u = v.u;
  return (unsigned short)((u + 0x7FFFu + ((u >> 16) & 1u)) >> 16);
}

// Convert fp32 [rows][K_REAL] -> bf16 [rows][K_PAD], zero-filling the pad
// tail. Handles BOTH x (rows 0..4095) and sw (rows 4096..6143) in one launch.
__global__ void convert_pad_kernel(const float* __restrict__ x,
                                   const float* __restrict__ sw,
                                   unsigned short* __restrict__ dst) {
  const int KB = K_PAD / 8;  // 168 8-element blocks per row
  const int total = (M_ROWS + NU) * KB;
  for (int idx = blockIdx.x * blockDim.x + threadIdx.x; idx < total;
       idx += gridDim.x * blockDim.x) {
    int r  = idx / KB;
    int kb = idx - r * KB;
    int k0 = kb * 8;
    uint32_t p0 = 0, p1 = 0, p2 = 0, p3 = 0;
    if (k0 + 8 <= K_REAL) {  // K_REAL % 8 == 0: blocks are all-real or all-pad
      const float* srow = (r < M_ROWS) ? (x + (size_t)r * K_REAL)
                                       : (sw + (size_t)(r - M_ROWS) * K_REAL);
      const float4* s = (const float4*)(srow + k0);
      float4 f0 = s[0];
      float4 f1 = s[1];
      p0 = (uint32_t)f2bf_rne(f0.x) | ((uint32_t)f2bf_rne(f0.y) << 16);
      p1 = (uint32_t)f2bf_rne(f0.z) | ((uint32_t)f2bf_rne(f0.w) << 16);
      p2 = (uint32_t)f2bf_rne(f1.x) | ((uint32_t)f2bf_rne(f1.y) << 16);
      p3 = (uint32_t)f2bf_rne(f1.z) | ((uint32_t)f2bf_rne(f1.w) << 16);
    }
    uint4 o; o.x = p0; o.y = p1; o.z = p2; o.w = p3;
    *(uint4*)(dst + (size_t)r * K_PAD + k0) = o;
  }
}

// ---------------------------------------------------------------------------
// 256x256 fused GEMM, split-K=2, R9's ring-4 ks-slot schedule (R12).
// Rationale: staged-bytes/time ~= 8-10 TB/s invariant across R1-R11 ->
// minimize staged bytes: 256x256 = 176 MB total (vs 264 MB at 256x128).
// Split-K=2 keeps grid at 256 blocks (1/CU).  8 waves = 2M x 4N; per wave
// 8x4 16x16x32 frags (128 AGPR acc).  LDS 128KB: ring of 4 ks-slots, each
// A[256x32] 16KB + B[256x32] 16KB.  SLOT = 4 gload_lds per thread.
// Phase s (21 per split): { stage ks s+3 -> slot (s+3)%4 | ds_read frags
//   slot s%4 -> s_barrier -> 32 MFMA (setprio) -> vmcnt(8) -> s_barrier }.
// vmcnt(8) = 2 slots (8 loads) outstanding -> slot s+1 landed.  Overwrite
// safety: slot (s+3)%4 == (s-1)%4 last read phase s-1, drained before its
// closing barrier.  Tail: VMW 8,8,4,0.
// Swizzle (16B chunks, involution): phys chunk p holds logical p^((p>>3)&3);
// read byte = row*64 + (g*16 ^ (((rl>>1)&3)<<4)).  (0 conflicts R5-R11.)
// XCD mapping: xcd -> (split, 4 tileM x 8 tileN) rectangle: A 1.4MB + B-split
// 2.75MB ~= 4.1MB per XCD L2.
// ---------------------------------------------------------------------------
__global__ __launch_bounds__(512, 1)
void fused_readout_gemm(const unsigned short* __restrict__ Abf,  // [M_ROWS][K_PAD]
                        const unsigned short* __restrict__ Bbf,  // [NU][K_PAD]
                        const float* __restrict__ fw,            // [NU][NC]
                        float* __restrict__ part) {              // [2][NB][NU]
  __shared__ unsigned short As[4][8192];  // slot: 256 rows x 32 (16KB)
  __shared__ unsigned short Bs[4][8192];  // slot: 256 rows x 32 (16KB)

  const int tid  = threadIdx.x;
  const int lane = tid & 63;
  const int w    = tid >> 6;    // 0..7
  const int wm   = w >> 2;      // 0..1: 128-row group (2 batches each)
  const int wn   = w & 3;       // 0..3: 64-col group
  const int g    = lane >> 4;   // k-group 0..3
  const int rl   = lane & 15;

  // XCD mapping: xcd owns (split = xcd>>2, tileM quad = xcd&3) x 8 tileN.
  const int braw  = (int)blockIdx.x;
  const int xcd   = braw & 7;
  const int idx   = braw >> 3;             // 0..31
  const int split = xcd >> 2;              // 0..1
  const int tileM = (xcd & 3) * 4 + (idx & 3);   // 0..15
  const int tileN = idx >> 2;              // 0..7
  const int rowA0 = tileM * BM;
  const int colB0 = tileN * BN;
  const int kS    = split * K_SPLIT;

  // Pre-swizzled staging sources. Thread stages phys chunks {tid, 512+tid}
  // of each 1024-chunk plane; logical chunk = p ^ ((p>>3)&3) (+512 offset
  // preserves low 5 bits -> second chunk is row +128).
  const int lc  = tid ^ ((tid >> 3) & 3);
  const int sr  = lc >> 2;   // 0..127
  const int sc  = lc & 3;
  const unsigned short* srcA = Abf + (size_t)(rowA0 + sr) * K_PAD + kS + sc * 8;
  const unsigned short* srcB = Bbf + (size_t)(colB0 + sr) * K_PAD + kS + sc * 8;

  // Read-side byte offset within a slot plane (swizzle folded in).
  const int laneOff = rl * 64 + ((g * 16) ^ (((rl >> 1) & 3) << 4));

#define GLOAD(dst, src)                                                         \
  __builtin_amdgcn_global_load_lds(                                             \
      (const __attribute__((address_space(1))) unsigned int*)(const void*)(src),\
      (__attribute__((address_space(3))) unsigned int*)(void*)(dst), 16, 0, 0)

  // Stage one ks-step (elements [koff, koff+32)) into slot j: 4 loads.
#define SLOT(j, koff)                                                           \
  do {                                                                          \
    char* _pa = (char*)&As[j][0];                                               \
    GLOAD(_pa + tid * 16, srcA + (koff));                                       \
    GLOAD(_pa + 8192 + tid * 16, srcA + (size_t)128 * K_PAD + (koff));          \
    char* _pb = (char*)&Bs[j][0];                                               \
    GLOAD(_pb + tid * 16, srcB + (koff));                                       \
    GLOAD(_pb + 8192 + tid * 16, srcB + (size_t)128 * K_PAD + (koff));          \
  } while (0)

#define LDFRAGS(j)                                                              \
  do {                                                                          \
    const char* _pa = (const char*)&As[j][0] + wm * 8192 + laneOff;             \
    _Pragma("unroll") for (int _i = 0; _i < 8; ++_i)                            \
      av[_i] = *(const bf16x8*)(_pa + _i * 1024);                               \
    const char* _pb = (const char*)&Bs[j][0] + wn * 4096 + laneOff;             \
    _Pragma("unroll") for (int _i = 0; _i < 4; ++_i)                            \
      bv[_i] = *(const bf16x8*)(_pb + _i * 1024);                               \
  } while (0)

#define MFMA32()                                                                \
  do {                                                                          \
    __builtin_amdgcn_s_setprio(1);                                              \
    _Pragma("unroll") for (int _m = 0; _m < 8; ++_m)                            \
      _Pragma("unroll") for (int _n = 0; _n < 4; ++_n)                          \
        acc[_m][_n] = __builtin_amdgcn_mfma_f32_16x16x32_bf16(                  \
            av[_m], bv[_n], acc[_m][_n], 0, 0, 0);                              \
    __builtin_amdgcn_s_setprio(0);                                              \
  } while (0)

#define BAR()                                                                   \
  do { __builtin_amdgcn_s_barrier(); __builtin_amdgcn_sched_barrier(0); } while (0)
#define VMW(N)                                                                  \
  do { asm volatile("s_waitcnt vmcnt(" #N ")" ::: "memory");                    \
       __builtin_amdgcn_sched_barrier(0); } while (0)

  f32x4 acc[8][4];
#pragma unroll
  for (int m = 0; m < 8; ++m)
#pragma unroll
    for (int n = 0; n < 4; ++n) acc[m][n] = (f32x4)0.f;

  bf16x8 av[8], bv[4];

  // Prologue: slots 0..2 <- ks 0..2 (12 loads); wait for ks0 (oldest 4).
  SLOT(0, 0); SLOT(1, 32); SLOT(2, 64);
  VMW(8); BAR();

  int kb = 96;   // element offset of ks (s+3) at s = 4*it
#pragma unroll 1
  for (int it = 0; it < 4; ++it) {   // phases s = 4it .. 4it+3  (s = 0..15)
    SLOT(3, kb);      LDFRAGS(0); BAR(); MFMA32(); VMW(8); BAR();
    SLOT(0, kb + 32); LDFRAGS(1); BAR(); MFMA32(); VMW(8); BAR();
    SLOT(1, kb + 64); LDFRAGS(2); BAR(); MFMA32(); VMW(8); BAR();
    SLOT(2, kb + 96); LDFRAGS(3); BAR(); MFMA32(); VMW(8); BAR();
    kb += 128;
  }
  // Tail: s = 16..20 (kb == 608 == ks19*32)
  SLOT(3, 608); LDFRAGS(0); BAR(); MFMA32(); VMW(8); BAR();  // s=16 stage ks19
  SLOT(0, 640); LDFRAGS(1); BAR(); MFMA32(); VMW(8); BAR();  // s=17 stage ks20
  LDFRAGS(2);               BAR(); MFMA32(); VMW(4); BAR();  // s=18
  LDFRAGS(3);               BAR(); MFMA32(); VMW(0); BAR();  // s=19
  LDFRAGS(0);               BAR(); MFMA32();                 // s=20 (slot0=ks20)

#undef GLOAD
#undef SLOT
#undef LDFRAGS
#undef MFMA32
#undef BAR
#undef VMW

  // Epilogue: wave's 128 rows = 2 batches (half = 0/1).
  // acc[half*4+m2][ni] elem j = G(c = m2*16+g*4+j,
  //                               u = colB0 + wn*64 + ni*16 + rl)
  // for batch bidx = tileM*4 + wm*2 + half.   (R5-verified mapping.)
  const int ubase = colB0 + wn * 64;
#pragma unroll
  for (int half = 0; half < 2; ++half) {
    float vtmp[4];
#pragma unroll
    for (int ni = 0; ni < 4; ++ni) {
      const int u = ubase + ni * 16 + rl;
      const float* fwrow = fw + (size_t)u * NC;
      float t = 0.f;
#pragma unroll
      for (int m2 = 0; m2 < 4; ++m2) {
        float4 w4 = *(const float4*)(fwrow + m2 * 16 + g * 4);
        f32x4 a_ = acc[half * 4 + m2][ni];
        t += w4.x * a_[0] + w4.y * a_[1] + w4.z * a_[2] + w4.w * a_[3];
      }
      t += __shfl_xor(t, 16, 64);   // reduce across k-groups (lanes ^16, ^32)
      t += __shfl_xor(t, 32, 64);
      vtmp[ni] = t;
    }
    const int bidx = tileM * 4 + wm * 2 + half;
    const int ucol = ubase + lane;   // = ubase + g*16 + rl
    float r = (g == 0) ? vtmp[0] : (g == 1) ? vtmp[1]
            : (g == 2) ? vtmp[2] : vtmp[3];
    part[((size_t)split * NB + bidx) * NU + ucol] = r;
  }
}

// out[b,u] = part[0][b][u] + part[1][b][u] + bias[u]
__global__ __launch_bounds__(256)
void combine_kernel(const float* __restrict__ part,
                    const float* __restrict__ bias,
                    float* __restrict__ out) {
  int f = blockIdx.x * blockDim.x + threadIdx.x;  // float4 index, 0..32767
  const float4* p0 = (const float4*)part;
  const float4* p1 = (const float4*)(part + (size_t)NB * NU);
  const float4* bz = (const float4*)bias;
  float4 a = p0[f];
  float4 b = p1[f];
  float4 c = bz[f & 511];
  float4 o;
  o.x = a.x + b.x + c.x;
  o.y = a.y + b.y + c.y;
  o.z = a.z + b.z + c.z;
  o.w = a.w + b.w + c.w;
  ((float4*)out)[f] = o;
}

extern "C" void kernel_launch(void* const* d_in, const int* in_sizes, int n_in,
                              void* d_out, int out_size, void* d_ws, size_t ws_size,
                              hipStream_t stream) {
  const float* x    = (const float*)d_in[0];  // [64,64,36,36]
  const float* fw   = (const float*)d_in[1];  // [2048,64,1,1]
  const float* bias = (const float*)d_in[2];  // [2048]
  const float* sw   = (const float*)d_in[3];  // [2048,36,36]
  float* out = (float*)d_out;                 // [64][2048]

  unsigned short* Abf = (unsigned short*)d_ws;            // 4096*1344*2 B
  unsigned short* Bbf = Abf + (size_t)M_ROWS * K_PAD;     // 2048*1344*2 B
  float* part = (float*)(Bbf + (size_t)NU * K_PAD);       // 2*64*2048*4 B

  // Convert + zero-pad both inputs to bf16 (K-major), one launch
  {
    int total = (M_ROWS + NU) * (K_PAD / 8);
    int blocks = (total + 255) / 256;
    if (blocks > 2048) blocks = 2048;
    convert_pad_kernel<<<blocks, 256, 0, stream>>>(x, sw, Abf);
  }

  // Fused split-K GEMM + readout: 2 splits x 16 M-tiles x 8 N-tiles = 256
  fused_readout_gemm<<<dim3(256), 512, 0, stream>>>(Abf, Bbf, fw, part);

  // Cross-split combine + bias
  combine_kernel<<<dim3((NB * NU / 4) / 256), 256, 0, stream>>>(part, bias, out);
}

// Round 13
// 45.504 us; speedup vs baseline: 1.1750x; 1.1750x over previous
//
#include <hip/hip_runtime.h>
#include <hip/hip_bf16.h>
#include <stdint.h>

// Problem geometry
#define NB 64          // batch
#define NC 64          // C_IN
#define NU 2048        // N_UNITS
#define K_REAL 1296    // H*W = 36*36
#define K_PAD  1344    // 21 K-tiles of 64 (3.7% pad)
#define M_ROWS 4096    // NB*NC

// GEMM tile
#define BM 256
#define BN 128

typedef __attribute__((ext_vector_type(4))) float f32x4;
typedef __attribute__((ext_vector_type(8))) short bf16x8;

__device__ __forceinline__ unsigned short f2bf_rne(float f) {
  union { float f; uint32_t u; } v; v.f = f;
  uint32_t u = v.u;
  return (unsigned short)((u + 0x7FFFu + ((u >> 16) & 1u)) >> 16);
}

// Convert fp32 [rows][K_REAL] -> bf16 [rows][K_PAD], zero-filling the pad
// tail. Handles BOTH x (rows 0..4095) and sw (rows 4096..6143) in one launch.
__global__ void convert_pad_kernel(const float* __restrict__ x,
                                   const float* __restrict__ sw,
                                   unsigned short* __restrict__ dst) {
  const int KB = K_PAD / 8;  // 168 8-element blocks per row
  const int total = (M_ROWS + NU) * KB;
  for (int idx = blockIdx.x * blockDim.x + threadIdx.x; idx < total;
       idx += gridDim.x * blockDim.x) {
    int r  = idx / KB;
    int kb = idx - r * KB;
    int k0 = kb * 8;
    uint32_t p0 = 0, p1 = 0, p2 = 0, p3 = 0;
    if (k0 + 8 <= K_REAL) {  // K_REAL % 8 == 0: blocks are all-real or all-pad
      const float* srow = (r < M_ROWS) ? (x + (size_t)r * K_REAL)
                                       : (sw + (size_t)(r - M_ROWS) * K_REAL);
      const float4* s = (const float4*)(srow + k0);
      float4 f0 = s[0];
      float4 f1 = s[1];
      p0 = (uint32_t)f2bf_rne(f0.x) | ((uint32_t)f2bf_rne(f0.y) << 16);
      p1 = (uint32_t)f2bf_rne(f0.z) | ((uint32_t)f2bf_rne(f0.w) << 16);
      p2 = (uint32_t)f2bf_rne(f1.x) | ((uint32_t)f2bf_rne(f1.y) << 16);
      p3 = (uint32_t)f2bf_rne(f1.z) | ((uint32_t)f2bf_rne(f1.w) << 16);
    }
    uint4 o; o.x = p0; o.y = p1; o.z = p2; o.w = p3;
    *(uint4*)(dst + (size_t)r * K_PAD + k0) = o;
  }
}

// ---------------------------------------------------------------------------
// 256x128 fused GEMM, BK=64 phases, ring-3 double-slot pipeline (R13).
// Same geometry/swizzle/epilogue/XCD map as R9 (best measured); the change:
// 21 barrier-phases instead of 42 — per-phase fixed overhead (~1100 cyc of
// barrier release + cross-wave waitcnt propagation) is paid half as often.
// 8 waves = 4M x 2N; per wave 4x4 16x16x32 frags per ks-half (64 AGPR acc).
// LDS 144KB: ring of 3 slots; slot = one BK=64 K-tile, stored as two
// 32-wide half-planes (A[256x32] 16KB x2 + B[128x32] 8KB x2 = 48KB).
// Phase p (slot p%3): { SLOT(p+2 -> (p+2)%3, 6 loads) | LDF half0
//   -> BAR -> LDF half1 | 16 MFMA(h0) | 16 MFMA(h1) -> VMW(6) -> BAR }.
// Landed-guarantee: phase p-1's VMW(6) leaves only slot p+1's 6 loads
// outstanding (vmcnt retires in issue order) -> slot p landed per-wave; the
// closing BAR makes it cross-wave. Overwrite: stage at p targets (p-1)%3,
// whose ds_reads retired before p-1's closing BAR (lgkm drained pre-MFMA).
// Tail: p=19 VMW(0), p=20 no stage/no closing.
// Swizzle (16B chunks, involution): phys chunk c holds logical c^((c>>3)&3);
// read byte = row*64 + (g*16 ^ (((rl>>1)&3)<<4)).  (0 conflicts R5-R12.)
// ---------------------------------------------------------------------------
__global__ __launch_bounds__(512, 1)
void fused_readout_gemm(const unsigned short* __restrict__ Abf,  // [M_ROWS][K_PAD]
                        const unsigned short* __restrict__ Bbf,  // [NU][K_PAD]
                        const float* __restrict__ fw,            // [NU][NC]
                        const float* __restrict__ bias,          // [NU]
                        float* __restrict__ out) {               // [NB][NU]
  __shared__ unsigned short As[3][2][8192];  // [slot][half][256 x 32] 16KB
  __shared__ unsigned short Bs[3][2][4096];  // [slot][half][128 x 32]  8KB

  const int tid  = threadIdx.x;
  const int lane = tid & 63;
  const int w    = tid >> 6;    // 0..7
  const int wm   = w >> 1;      // 0..3: 64-row group (one batch each)
  const int wn   = w & 1;       // 0..1: 64-col group
  const int g    = lane >> 4;   // k-group 0..3
  const int rl   = lane & 15;

  // XCD mapping: xcd = braw&7 owns a 4(tileM) x 8(tileN) rectangle.
  const int braw  = (int)blockIdx.x;
  const int xcd   = braw & 7;
  const int idx   = braw >> 3;           // 0..31
  const int tileM = (xcd >> 1) * 4 + (idx & 3);
  const int tileN = (xcd & 1) * 8 + (idx >> 2);
  const int rowA0 = tileM * BM;
  const int colB0 = tileN * BN;

  // Pre-swizzled staging sources (identical to R9). Thread stages A phys
  // chunks {tid, 512+tid} and B phys chunk {tid} of each half-plane;
  // logical chunk = p ^ ((p>>3)&3).
  const int lc  = tid ^ ((tid >> 3) & 3);
  const int sr  = lc >> 2;   // 0..127
  const int sc  = lc & 3;
  const unsigned short* srcA = Abf + (size_t)(rowA0 + sr) * K_PAD + sc * 8;
  const unsigned short* srcB = Bbf + (size_t)(colB0 + sr) * K_PAD + sc * 8;

  // Read-side byte offset within a half-plane (swizzle folded in).
  const int laneOff = rl * 64 + ((g * 16) ^ (((rl >> 1) & 3) << 4));

#define GLOAD(dst, src)                                                         \
  __builtin_amdgcn_global_load_lds(                                             \
      (const __attribute__((address_space(1))) unsigned int*)(const void*)(src),\
      (__attribute__((address_space(3))) unsigned int*)(void*)(dst), 16, 0, 0)

  // Stage one BK=64 K-tile (elements [koff, koff+64)) into slot j: 6 loads.
#define SLOT(j, koff)                                                           \
  do {                                                                          \
    char* _pa0 = (char*)&As[j][0][0];                                           \
    GLOAD(_pa0 + tid * 16, srcA + (koff));                                      \
    GLOAD(_pa0 + 8192 + tid * 16, srcA + (size_t)128 * K_PAD + (koff));         \
    char* _pa1 = (char*)&As[j][1][0];                                           \
    GLOAD(_pa1 + tid * 16, srcA + (koff) + 32);                                 \
    GLOAD(_pa1 + 8192 + tid * 16, srcA + (size_t)128 * K_PAD + (koff) + 32);    \
    GLOAD((char*)&Bs[j][0][0] + tid * 16, srcB + (koff));                       \
    GLOAD((char*)&Bs[j][1][0] + tid * 16, srcB + (koff) + 32);                  \
  } while (0)

  // Load one half-plane's fragments into the given register sets.
#define LDF(j, h, AV, BV)                                                       \
  do {                                                                          \
    const char* _pa = (const char*)&As[j][h][0] + wm * 4096 + laneOff;          \
    AV[0] = *(const bf16x8*)(_pa);                                              \
    AV[1] = *(const bf16x8*)(_pa + 1024);                                       \
    AV[2] = *(const bf16x8*)(_pa + 2048);                                       \
    AV[3] = *(const bf16x8*)(_pa + 3072);                                       \
    const char* _pb = (const char*)&Bs[j][h][0] + wn * 4096 + laneOff;          \
    BV[0] = *(const bf16x8*)(_pb);                                              \
    BV[1] = *(const bf16x8*)(_pb + 1024);                                       \
    BV[2] = *(const bf16x8*)(_pb + 2048);                                       \
    BV[3] = *(const bf16x8*)(_pb + 3072);                                       \
  } while (0)

#define MFMA16(AV, BV)                                                          \
  do {                                                                          \
    __builtin_amdgcn_s_setprio(1);                                              \
    _Pragma("unroll") for (int _m = 0; _m < 4; ++_m)                            \
      _Pragma("unroll") for (int _n = 0; _n < 4; ++_n)                          \
        acc[_m][_n] = __builtin_amdgcn_mfma_f32_16x16x32_bf16(                  \
            AV[_m], BV[_n], acc[_m][_n], 0, 0, 0);                              \
    __builtin_amdgcn_s_setprio(0);                                              \
  } while (0)

#define BAR()                                                                   \
  do { __builtin_amdgcn_s_barrier(); __builtin_amdgcn_sched_barrier(0); } while (0)
#define VMW(N)                                                                  \
  do { asm volatile("s_waitcnt vmcnt(" #N ")" ::: "memory");                    \
       __builtin_amdgcn_sched_barrier(0); } while (0)

  f32x4 acc[4][4];
#pragma unroll
  for (int m = 0; m < 4; ++m)
#pragma unroll
    for (int n = 0; n < 4; ++n) acc[m][n] = (f32x4)0.f;

  bf16x8 av0[4], bv0[4], av1[4], bv1[4];

  // Prologue: slots 0,1 <- K-tiles 0,1 (12 loads); VMW(6) -> slot 0 landed.
  SLOT(0, 0); SLOT(1, 64);
  VMW(6); BAR();

  int kb = 0;   // 64*3*it
#pragma unroll 1
  for (int it = 0; it < 6; ++it) {   // phases p = 3it .. 3it+2  (p = 0..17)
    // p = 3it+0: read slot 0, stage K-tile p+2 -> slot 2
    SLOT(2, kb + 128); LDF(0, 0, av0, bv0); BAR(); LDF(0, 1, av1, bv1);
    MFMA16(av0, bv0); MFMA16(av1, bv1); VMW(6); BAR();
    // p = 3it+1: read slot 1, stage -> slot 0
    SLOT(0, kb + 192); LDF(1, 0, av0, bv0); BAR(); LDF(1, 1, av1, bv1);
    MFMA16(av0, bv0); MFMA16(av1, bv1); VMW(6); BAR();
    // p = 3it+2: read slot 2, stage -> slot 1
    SLOT(1, kb + 256); LDF(2, 0, av0, bv0); BAR(); LDF(2, 1, av1, bv1);
    MFMA16(av0, bv0); MFMA16(av1, bv1); VMW(6); BAR();
    kb += 192;
  }
  // p=18: read slot 0, stage K-tile 20 (offset 1280) -> slot 2
  SLOT(2, 1280); LDF(0, 0, av0, bv0); BAR(); LDF(0, 1, av1, bv1);
  MFMA16(av0, bv0); MFMA16(av1, bv1); VMW(6); BAR();
  // p=19: read slot 1; drain slot 2's loads
  LDF(1, 0, av0, bv0); BAR(); LDF(1, 1, av1, bv1);
  MFMA16(av0, bv0); MFMA16(av1, bv1); VMW(0); BAR();
  // p=20: read slot 2; done
  LDF(2, 0, av0, bv0); BAR(); LDF(2, 1, av1, bv1);
  MFMA16(av0, bv0); MFMA16(av1, bv1);

#undef GLOAD
#undef SLOT
#undef LDF
#undef MFMA16
#undef BAR
#undef VMW

  // Epilogue (R9-verified): wave's 64 rows = one batch (bidx = tileM*4 + wm).
  // acc[m][n] elem j = G(c = m*16 + g*4 + j, u = colB0 + wn*64 + n*16 + rl).
  const int bidx = tileM * 4 + wm;
  float vtmp[4];
#pragma unroll
  for (int n = 0; n < 4; ++n) {
    const int u = colB0 + wn * 64 + n * 16 + rl;
    const float* fwrow = fw + (size_t)u * NC;
    float s = 0.f;
#pragma unroll
    for (int m = 0; m < 4; ++m) {
      float4 w4 = *(const float4*)(fwrow + m * 16 + g * 4);
      f32x4 a_ = acc[m][n];
      s += w4.x * a_[0] + w4.y * a_[1] + w4.z * a_[2] + w4.w * a_[3];
    }
    s += __shfl_xor(s, 16, 64);   // reduce across k-groups (lanes ^16, ^32)
    s += __shfl_xor(s, 32, 64);
    vtmp[n] = s;
  }
  const int ucol = colB0 + wn * 64 + lane;
  float r = (g == 0) ? vtmp[0] : (g == 1) ? vtmp[1] : (g == 2) ? vtmp[2] : vtmp[3];
  out[(size_t)bidx * NU + ucol] = r + bias[ucol];
}

extern "C" void kernel_launch(void* const* d_in, const int* in_sizes, int n_in,
                              void* d_out, int out_size, void* d_ws, size_t ws_size,
                              hipStream_t stream) {
  const float* x    = (const float*)d_in[0];  // [64,64,36,36]
  const float* fw   = (const float*)d_in[1];  // [2048,64,1,1]
  const float* bias = (const float*)d_in[2];  // [2048]
  const float* sw   = (const float*)d_in[3];  // [2048,36,36]
  float* out = (float*)d_out;                 // [64][2048]

  unsigned short* Abf = (unsigned short*)d_ws;            // 4096*1344*2 B
  unsigned short* Bbf = Abf + (size_t)M_ROWS * K_PAD;     // 2048*1344*2 B

  // Convert + zero-pad both inputs to bf16 (K-major), one launch
  {
    int total = (M_ROWS + NU) * (K_PAD / 8);
    int blocks = (total + 255) / 256;
    if (blocks > 2048) blocks = 2048;
    convert_pad_kernel<<<blocks, 256, 0, stream>>>(x, sw, Abf);
  }

  // Fused GEMM + readout + bias: 16 M-tiles x 16 N-tiles = 256 blocks
  fused_readout_gemm<<<dim3(256), 512, 0, stream>>>(Abf, Bbf, fw, bias, out);
}

// Round 14
// 44.453 us; speedup vs baseline: 1.2027x; 1.0236x over previous
//
#include <hip/hip_runtime.h>
#include <hip/hip_bf16.h>
#include <stdint.h>

// Problem geometry
#define NB 64          // batch
#define NC 64          // C_IN
#define NU 2048        // N_UNITS
#define K_REAL 1296    // H*W = 36*36
#define K_PAD  1344    // 2 splits x 21 ks-steps of 32
#define M_ROWS 4096    // NB*NC
#define K_SPLIT 672

// GEMM tile
#define BM 256
#define BN 128

typedef __attribute__((ext_vector_type(4))) float f32x4;
typedef __attribute__((ext_vector_type(8))) short bf16x8;

__device__ __forceinline__ unsigned short f2bf_rne(float f) {
  union { float f; uint32_t u; } v; v.f = f;
  uint32_t u = v.u;
  return (unsigned short)((u + 0x7FFFu + ((u >> 16) & 1u)) >> 16);
}

// Convert fp32 [rows][K_REAL] -> bf16 [rows][K_PAD], zero-filling the pad
// tail. Handles BOTH x (rows 0..4095) and sw (rows 4096..6143) in one launch.
__global__ void convert_pad_kernel(const float* __restrict__ x,
                                   const float* __restrict__ sw,
                                   unsigned short* __restrict__ dst) {
  const int KB = K_PAD / 8;  // 168 8-element blocks per row
  const int total = (M_ROWS + NU) * KB;
  for (int idx = blockIdx.x * blockDim.x + threadIdx.x; idx < total;
       idx += gridDim.x * blockDim.x) {
    int r  = idx / KB;
    int kb = idx - r * KB;
    int k0 = kb * 8;
    uint32_t p0 = 0, p1 = 0, p2 = 0, p3 = 0;
    if (k0 + 8 <= K_REAL) {  // K_REAL % 8 == 0: blocks are all-real or all-pad
      const float* srow = (r < M_ROWS) ? (x + (size_t)r * K_REAL)
                                       : (sw + (size_t)(r - M_ROWS) * K_REAL);
      const float4* s = (const float4*)(srow + k0);
      float4 f0 = s[0];
      float4 f1 = s[1];
      p0 = (uint32_t)f2bf_rne(f0.x) | ((uint32_t)f2bf_rne(f0.y) << 16);
      p1 = (uint32_t)f2bf_rne(f0.z) | ((uint32_t)f2bf_rne(f0.w) << 16);
      p2 = (uint32_t)f2bf_rne(f1.x) | ((uint32_t)f2bf_rne(f1.y) << 16);
      p3 = (uint32_t)f2bf_rne(f1.z) | ((uint32_t)f2bf_rne(f1.w) << 16);
    }
    uint4 o; o.x = p0; o.y = p1; o.z = p2; o.w = p3;
    *(uint4*)(dst + (size_t)r * K_PAD + k0) = o;
  }
}

// ---------------------------------------------------------------------------
// 256x128 fused GEMM, split-K=2, ring-3 ks-slot pipeline, 2 BLOCKS/CU (R14).
// = R9's exact schedule (best measured, ~31us GEMM) with LDS cut to 72KB
// (ring-5 -> ring-3) so TWO independent barrier domains co-reside per CU
// (R11's proven per-byte efficiency: 16 B/cyc/CU vs 13.7 at 1 block/CU).
// 8 waves = 4M x 2N; per wave 4x4 16x16x32 frags (64 AGPR acc).
// __launch_bounds__(512,4): total regs <= 128 -> 16 waves/CU = 2 blocks.
// LDS 72KB: 3 slots x (A[256x32] 16KB + B[128x32] 8KB).
// Phase s (21 per split): { SLOT(ks s+2 -> slot (s+2)%3, 3 loads) |
//   LDFRAGS slot s%3 -> BAR -> 16 MFMA (setprio) -> vmcnt(3) -> BAR }.
// vmcnt(3): slot s+1 landed (only slot s+2's 3 loads outstanding).
// Overwrite: stage at s targets (s-1)%3, read phase s-1, drained before its
// closing BAR. Stages end at s=18 (ks20); tail VMW 3,0.
// Swizzle (16B chunks, involution): phys chunk c holds logical c^((c>>3)&3);
// read byte = row*64 + (g*16 ^ (((rl>>1)&3)<<4)).  (0 conflicts R5-R13.)
// XCD map: xcd -> (split = xcd>>2, tileM quad = xcd&3) x 16 tileN:
// A 1.4MB + B-split 2.75MB = 4.15MB per XCD L2.
// ---------------------------------------------------------------------------
__global__ __launch_bounds__(512, 4)
void fused_readout_gemm(const unsigned short* __restrict__ Abf,  // [M_ROWS][K_PAD]
                        const unsigned short* __restrict__ Bbf,  // [NU][K_PAD]
                        const float* __restrict__ fw,            // [NU][NC]
                        float* __restrict__ part) {              // [2][NB][NU]
  __shared__ unsigned short As[3][8192];  // slot: 256 rows x 32 (16KB)
  __shared__ unsigned short Bs[3][4096];  // slot: 128 rows x 32 (8KB)

  const int tid  = threadIdx.x;
  const int lane = tid & 63;
  const int w    = tid >> 6;    // 0..7
  const int wm   = w >> 1;      // 0..3: 64-row group (one batch each)
  const int wn   = w & 1;       // 0..1: 64-col group
  const int g    = lane >> 4;   // k-group 0..3
  const int rl   = lane & 15;

  // XCD mapping: xcd = braw&7 -> (split, tileM quad); idx -> tileM low, tileN.
  const int braw  = (int)blockIdx.x;
  const int xcd   = braw & 7;
  const int idx   = braw >> 3;             // 0..63
  const int split = xcd >> 2;              // 0..1
  const int tileM = (xcd & 3) * 4 + (idx & 3);   // 0..15
  const int tileN = idx >> 2;              // 0..15
  const int rowA0 = tileM * BM;
  const int colB0 = tileN * BN;
  const int kS    = split * K_SPLIT;

  // Pre-swizzled staging sources (R9-identical). Thread stages A phys chunks
  // {tid, 512+tid} and B phys chunk {tid}; logical chunk = p ^ ((p>>3)&3).
  const int lc  = tid ^ ((tid >> 3) & 3);
  const int sr  = lc >> 2;   // 0..127
  const int sc  = lc & 3;
  const unsigned short* srcA = Abf + (size_t)(rowA0 + sr) * K_PAD + kS + sc * 8;
  const unsigned short* srcB = Bbf + (size_t)(colB0 + sr) * K_PAD + kS + sc * 8;

  // Read-side byte offset within a slot plane (swizzle folded in).
  const int laneOff = rl * 64 + ((g * 16) ^ (((rl >> 1) & 3) << 4));

#define GLOAD(dst, src)                                                         \
  __builtin_amdgcn_global_load_lds(                                             \
      (const __attribute__((address_space(1))) unsigned int*)(const void*)(src),\
      (__attribute__((address_space(3))) unsigned int*)(void*)(dst), 16, 0, 0)

  // Stage one ks-step (elements [koff, koff+32)) into slot j: 3 loads.
#define SLOT(j, koff)                                                           \
  do {                                                                          \
    char* _pa = (char*)&As[j][0];                                               \
    GLOAD(_pa + tid * 16, srcA + (koff));                                       \
    GLOAD(_pa + 8192 + tid * 16, srcA + (size_t)128 * K_PAD + (koff));          \
    GLOAD((char*)&Bs[j][0] + tid * 16, srcB + (koff));                          \
  } while (0)

#define LDFRAGS(j)                                                              \
  do {                                                                          \
    const char* _pa = (const char*)&As[j][0] + wm * 4096 + laneOff;             \
    av[0] = *(const bf16x8*)(_pa);                                              \
    av[1] = *(const bf16x8*)(_pa + 1024);                                       \
    av[2] = *(const bf16x8*)(_pa + 2048);                                       \
    av[3] = *(const bf16x8*)(_pa + 3072);                                       \
    const char* _pb = (const char*)&Bs[j][0] + wn * 4096 + laneOff;             \
    bv[0] = *(const bf16x8*)(_pb);                                              \
    bv[1] = *(const bf16x8*)(_pb + 1024);                                       \
    bv[2] = *(const bf16x8*)(_pb + 2048);                                       \
    bv[3] = *(const bf16x8*)(_pb + 3072);                                       \
  } while (0)

#define MFMA16()                                                                \
  do {                                                                          \
    __builtin_amdgcn_s_setprio(1);                                              \
    _Pragma("unroll") for (int _m = 0; _m < 4; ++_m)                            \
      _Pragma("unroll") for (int _n = 0; _n < 4; ++_n)                          \
        acc[_m][_n] = __builtin_amdgcn_mfma_f32_16x16x32_bf16(                  \
            av[_m], bv[_n], acc[_m][_n], 0, 0, 0);                              \
    __builtin_amdgcn_s_setprio(0);                                              \
  } while (0)

#define BAR()                                                                   \
  do { __builtin_amdgcn_s_barrier(); __builtin_amdgcn_sched_barrier(0); } while (0)
#define VMW(N)                                                                  \
  do { asm volatile("s_waitcnt vmcnt(" #N ")" ::: "memory");                    \
       __builtin_amdgcn_sched_barrier(0); } while (0)

  f32x4 acc[4][4];
#pragma unroll
  for (int m = 0; m < 4; ++m)
#pragma unroll
    for (int n = 0; n < 4; ++n) acc[m][n] = (f32x4)0.f;

  bf16x8 av[4], bv[4];

  // Prologue: slots 0,1 <- ks 0,1 (6 loads); VMW(3) -> slot 0 landed.
  SLOT(0, 0); SLOT(1, 32);
  VMW(3); BAR();

  int kb = 64;   // element offset of ks (s+2) at s = 3*it
#pragma unroll 1
  for (int it = 0; it < 6; ++it) {   // phases s = 3it .. 3it+2  (s = 0..17)
    SLOT(2, kb);      LDFRAGS(0); BAR(); MFMA16(); VMW(3); BAR();
    SLOT(0, kb + 32); LDFRAGS(1); BAR(); MFMA16(); VMW(3); BAR();
    SLOT(1, kb + 64); LDFRAGS(2); BAR(); MFMA16(); VMW(3); BAR();
    kb += 96;
  }
  // Tail: s = 18..20 (kb == 640 == ks20*32)
  SLOT(2, 640); LDFRAGS(0); BAR(); MFMA16(); VMW(3); BAR();  // s=18 stage ks20
  LDFRAGS(1);               BAR(); MFMA16(); VMW(0); BAR();  // s=19
  LDFRAGS(2);               BAR(); MFMA16();                 // s=20

#undef GLOAD
#undef SLOT
#undef LDFRAGS
#undef MFMA16
#undef BAR
#undef VMW

  // Epilogue (R9-verified): wave's 64 rows = one batch (bidx = tileM*4 + wm).
  // acc[m][n] elem j = G(c = m*16 + g*4 + j, u = colB0 + wn*64 + n*16 + rl).
  const int bidx = tileM * 4 + wm;
  float vtmp[4];
#pragma unroll
  for (int n = 0; n < 4; ++n) {
    const int u = colB0 + wn * 64 + n * 16 + rl;
    const float* fwrow = fw + (size_t)u * NC;
    float s = 0.f;
#pragma unroll
    for (int m = 0; m < 4; ++m) {
      float4 w4 = *(const float4*)(fwrow + m * 16 + g * 4);
      f32x4 a_ = acc[m][n];
      s += w4.x * a_[0] + w4.y * a_[1] + w4.z * a_[2] + w4.w * a_[3];
    }
    s += __shfl_xor(s, 16, 64);   // reduce across k-groups (lanes ^16, ^32)
    s += __shfl_xor(s, 32, 64);
    vtmp[n] = s;
  }
  const int ucol = colB0 + wn * 64 + lane;
  float r = (g == 0) ? vtmp[0] : (g == 1) ? vtmp[1] : (g == 2) ? vtmp[2] : vtmp[3];
  part[((size_t)split * NB + bidx) * NU + ucol] = r;
}

// out[b,u] = part[0][b][u] + part[1][b][u] + bias[u]
__global__ __launch_bounds__(256)
void combine_kernel(const float* __restrict__ part,
                    const float* __restrict__ bias,
                    float* __restrict__ out) {
  int f = blockIdx.x * blockDim.x + threadIdx.x;  // float4 index, 0..32767
  const float4* p0 = (const float4*)part;
  const float4* p1 = (const float4*)(part + (size_t)NB * NU);
  const float4* bz = (const float4*)bias;
  float4 a = p0[f];
  float4 b = p1[f];
  float4 c = bz[f & 511];
  float4 o;
  o.x = a.x + b.x + c.x;
  o.y = a.y + b.y + c.y;
  o.z = a.z + b.z + c.z;
  o.w = a.w + b.w + c.w;
  ((float4*)out)[f] = o;
}

extern "C" void kernel_launch(void* const* d_in, const int* in_sizes, int n_in,
                              void* d_out, int out_size, void* d_ws, size_t ws_size,
                              hipStream_t stream) {
  const float* x    = (const float*)d_in[0];  // [64,64,36,36]
  const float* fw   = (const float*)d_in[1];  // [2048,64,1,1]
  const float* bias = (const float*)d_in[2];  // [2048]
  const float* sw   = (const float*)d_in[3];  // [2048,36,36]
  float* out = (float*)d_out;                 // [64][2048]

  unsigned short* Abf = (unsigned short*)d_ws;            // 4096*1344*2 B
  unsigned short* Bbf = Abf + (size_t)M_ROWS * K_PAD;     // 2048*1344*2 B
  float* part = (float*)(Bbf + (size_t)NU * K_PAD);       // 2*64*2048*4 B

  // Convert + zero-pad both inputs to bf16 (K-major), one launch
  {
    int total = (M_ROWS + NU) * (K_PAD / 8);
    int blocks = (total + 255) / 256;
    if (blocks > 2048) blocks = 2048;
    convert_pad_kernel<<<blocks, 256, 0, stream>>>(x, sw, Abf);
  }

  // Fused split-K GEMM + readout: 2 splits x 16 tileM x 16 tileN = 512 blocks
  fused_readout_gemm<<<dim3(512), 512, 0, stream>>>(Abf, Bbf, fw, part);

  // Cross-split combine + bias
  combine_kernel<<<dim3((NB * NU / 4) / 256), 256, 0, stream>>>(part, bias, out);
}

// Round 15
// 42.260 us; speedup vs baseline: 1.2652x; 1.0519x over previous
//
#include <hip/hip_runtime.h>
#include <hip/hip_bf16.h>
#include <stdint.h>

// Problem geometry
#define NB 64          // batch
#define NC 64          // C_IN
#define NU 2048        // N_UNITS
#define K_REAL 1296    // H*W = 36*36
#define K_PAD  1344    // 42 ks-steps of 32 (3.7% pad)
#define M_ROWS 4096    // NB*NC

// GEMM tile
#define BM 256
#define BN 128
#define NKS 42         // 32-wide K-steps

typedef __attribute__((ext_vector_type(4))) float f32x4;
typedef __attribute__((ext_vector_type(8))) short bf16x8;

__device__ __forceinline__ unsigned short f2bf_rne(float f) {
  union { float f; uint32_t u; } v; v.f = f;
  uint32_t u = v.u;
  return (unsigned short)((u + 0x7FFFu + ((u >> 16) & 1u)) >> 16);
}

// Convert fp32 [rows][K_REAL] -> bf16 [rows][K_PAD], zero-filling the pad
// tail. Handles BOTH x (rows 0..4095) and sw (rows 4096..6143) in one launch.
// Grid sized for exactly 2 items/thread (2016*256*2 == 6144*168) — no ragged
// grid-stride tail.
__global__ void convert_pad_kernel(const float* __restrict__ x,
                                   const float* __restrict__ sw,
                                   unsigned short* __restrict__ dst) {
  const int KB = K_PAD / 8;  // 168 8-element blocks per row
  const int total = (M_ROWS + NU) * KB;
  for (int idx = blockIdx.x * blockDim.x + threadIdx.x; idx < total;
       idx += gridDim.x * blockDim.x) {
    int r  = idx / KB;
    int kb = idx - r * KB;
    int k0 = kb * 8;
    uint32_t p0 = 0, p1 = 0, p2 = 0, p3 = 0;
    if (k0 + 8 <= K_REAL) {  // K_REAL % 8 == 0: blocks are all-real or all-pad
      const float* srow = (r < M_ROWS) ? (x + (size_t)r * K_REAL)
                                       : (sw + (size_t)(r - M_ROWS) * K_REAL);
      const float4* s = (const float4*)(srow + k0);
      float4 f0 = s[0];
      float4 f1 = s[1];
      p0 = (uint32_t)f2bf_rne(f0.x) | ((uint32_t)f2bf_rne(f0.y) << 16);
      p1 = (uint32_t)f2bf_rne(f0.z) | ((uint32_t)f2bf_rne(f0.w) << 16);
      p2 = (uint32_t)f2bf_rne(f1.x) | ((uint32_t)f2bf_rne(f1.y) << 16);
      p3 = (uint32_t)f2bf_rne(f1.z) | ((uint32_t)f2bf_rne(f1.w) << 16);
    }
    uint4 o; o.x = p0; o.y = p1; o.z = p2; o.w = p3;
    *(uint4*)(dst + (size_t)r * K_PAD + k0) = o;
  }
}

// ---------------------------------------------------------------------------
// 256x128 fused GEMM, ring-of-5 ks-slot pipeline (R9 — session best, 42.2us).
// 8 waves = 4M x 2N; per wave 4x4 16x16x32 MFMA frags (64 AGPR acc).
// LDS 120KB: 5 slots, each one 32-wide K-step: A[256x32] (16KB) + B[128x32]
// (8KB). Slot(s) = s % 5. Phase s: { ds_read frags of slot s | stage ks s+4
// into slot (s+4)%5 -> BAR -> 16 MFMA (setprio) -> vmcnt(9) -> BAR }.
// vmcnt(9) = 3 slots (9 loads) in flight; slot staged 4 phases before read.
// Overwrite-safety: slot (s+4)%5 == (s-1)%5 was last READ in phase s-1; all
// waves' reads completed before the phase-(s-1) closing barrier (lgkmcnt
// drained before their MFMAs), and the stage is issued after that barrier.
// Tail (no stage after phase 37): VMW 9,9,9,6,3,0 then final MFMA.
// Swizzle (16B chunks, involution): phys chunk p holds logical p^((p>>3)&3);
// read addr byte = row*64 + (g*16 ^ (((rl>>1)&3)<<4)).  (0 conflicts, R5-R14.)
// XCD mapping: 4 tileM x 8 tileN rectangle per XCD -> per-XCD L2 working set
// 4x0.69 + 8x0.34 = 5.5 MB.
//
// Session ledger (why this config): 14 variants spanning occupancy 1-4
// blocks/CU, BK 32/64, tiles 128^2-256^2, ring 2-5, split-K 1/2/4, pins
// on/off all land 42-45us GEMM-side; this one measured best. The ~680 TF
// plateau is short-K (21-42 phases) pipeline fill/drain vs the 128-step
// steady state reference kernels enjoy at 4096^3 — structural at K=1344.
// ---------------------------------------------------------------------------
__global__ __launch_bounds__(512, 1)
void fused_readout_gemm(const unsigned short* __restrict__ Abf,  // [M_ROWS][K_PAD]
                        const unsigned short* __restrict__ Bbf,  // [NU][K_PAD]
                        const float* __restrict__ fw,            // [NU][NC]
                        const float* __restrict__ bias,          // [NU]
                        float* __restrict__ out) {               // [NB][NU]
  __shared__ unsigned short As[5][8192];  // slot: 256 rows x 32 (16KB)
  __shared__ unsigned short Bs[5][4096];  // slot: 128 rows x 32 (8KB)

  const int tid  = threadIdx.x;
  const int lane = tid & 63;
  const int w    = tid >> 6;    // 0..7
  const int wm   = w >> 1;      // 0..3: 64-row group (one batch each)
  const int wn   = w & 1;       // 0..1: 64-col group
  const int g    = lane >> 4;   // k-group 0..3
  const int rl   = lane & 15;

  // XCD mapping: xcd = braw&7 owns a 4(tileM) x 8(tileN) rectangle.
  const int braw  = (int)blockIdx.x;
  const int xcd   = braw & 7;
  const int idx   = braw >> 3;           // 0..31
  const int tileM = (xcd >> 1) * 4 + (idx & 3);
  const int tileN = (xcd & 1) * 8 + (idx >> 2);
  const int rowA0 = tileM * BM;
  const int colB0 = tileN * BN;

  // Pre-swizzled staging sources. Thread stages A phys chunks {tid, 512+tid}
  // and B phys chunk {tid}; logical chunk = p ^ ((p>>3)&3).
  const int lc  = tid ^ ((tid >> 3) & 3);
  const int sr  = lc >> 2;   // 0..127
  const int sc  = lc & 3;
  const unsigned short* srcA = Abf + (size_t)(rowA0 + sr) * K_PAD + sc * 8;
  const unsigned short* srcB = Bbf + (size_t)(colB0 + sr) * K_PAD + sc * 8;

  // Read-side byte offset within a slot plane (swizzle folded in).
  const int laneOff = rl * 64 + ((g * 16) ^ (((rl >> 1) & 3) << 4));

#define GLOAD(dst, src)                                                         \
  __builtin_amdgcn_global_load_lds(                                             \
      (const __attribute__((address_space(1))) unsigned int*)(const void*)(src),\
      (__attribute__((address_space(3))) unsigned int*)(void*)(dst), 16, 0, 0)

  // Stage one ks-step (elements [koff, koff+32) of K) into slot j.
#define SLOT(j, koff)                                                           \
  do {                                                                          \
    char* _pa = (char*)&As[j][0];                                               \
    GLOAD(_pa + tid * 16, srcA + (koff));                                       \
    GLOAD(_pa + 8192 + tid * 16, srcA + (size_t)128 * K_PAD + (koff));          \
    GLOAD((char*)&Bs[j][0] + tid * 16, srcB + (koff));                          \
  } while (0)

#define LDFRAGS(j)                                                              \
  do {                                                                          \
    const char* _pa = (const char*)&As[j][0] + wm * 4096 + laneOff;             \
    av[0] = *(const bf16x8*)(_pa);                                              \
    av[1] = *(const bf16x8*)(_pa + 1024);                                       \
    av[2] = *(const bf16x8*)(_pa + 2048);                                       \
    av[3] = *(const bf16x8*)(_pa + 3072);                                       \
    const char* _pb = (const char*)&Bs[j][0] + wn * 4096 + laneOff;             \
    bv[0] = *(const bf16x8*)(_pb);                                              \
    bv[1] = *(const bf16x8*)(_pb + 1024);                                       \
    bv[2] = *(const bf16x8*)(_pb + 2048);                                       \
    bv[3] = *(const bf16x8*)(_pb + 3072);                                       \
  } while (0)

#define MFMA16()                                                                \
  do {                                                                          \
    __builtin_amdgcn_s_setprio(1);                                              \
    _Pragma("unroll") for (int _m = 0; _m < 4; ++_m)                            \
      _Pragma("unroll") for (int _n = 0; _n < 4; ++_n)                          \
        acc[_m][_n] = __builtin_amdgcn_mfma_f32_16x16x32_bf16(                  \
            av[_m], bv[_n], acc[_m][_n], 0, 0, 0);                              \
    __builtin_amdgcn_s_setprio(0);                                              \
  } while (0)

#define BAR()                                                                   \
  do { __builtin_amdgcn_s_barrier(); __builtin_amdgcn_sched_barrier(0); } while (0)
#define VMW(N)                                                                  \
  do { asm volatile("s_waitcnt vmcnt(" #N ")" ::: "memory");                    \
       __builtin_amdgcn_sched_barrier(0); } while (0)

  f32x4 acc[4][4];
#pragma unroll
  for (int m = 0; m < 4; ++m)
#pragma unroll
    for (int n = 0; n < 4; ++n) acc[m][n] = (f32x4)0.f;

  bf16x8 av[4], bv[4];

  // Prologue: slots 0..3 <- ks 0..3 (12 loads); wait for ks0 (oldest 3).
  SLOT(0, 0); SLOT(1, 32); SLOT(2, 64); SLOT(3, 96);
  VMW(9); BAR();

  int kb = 128;   // element offset of ks (s+4) when s = it*5
#pragma unroll 1
  for (int it = 0; it < 7; ++it) {   // phases s = it*5 .. it*5+4  (s = 0..34)
    LDFRAGS(0); SLOT(4, kb);       BAR(); MFMA16(); VMW(9); BAR();
    LDFRAGS(1); SLOT(0, kb + 32);  BAR(); MFMA16(); VMW(9); BAR();
    LDFRAGS(2); SLOT(1, kb + 64);  BAR(); MFMA16(); VMW(9); BAR();
    LDFRAGS(3); SLOT(2, kb + 96);  BAR(); MFMA16(); VMW(9); BAR();
    LDFRAGS(4); SLOT(3, kb + 128); BAR(); MFMA16(); VMW(9); BAR();
    kb += 160;
  }
  // Tail: s = 35..41 (kb == 1248 == ks39*32)
  LDFRAGS(0); SLOT(4, 1248); BAR(); MFMA16(); VMW(9); BAR();  // s=35 stage ks39
  LDFRAGS(1); SLOT(0, 1280); BAR(); MFMA16(); VMW(9); BAR();  // s=36 stage ks40
  LDFRAGS(2); SLOT(1, 1312); BAR(); MFMA16(); VMW(9); BAR();  // s=37 stage ks41
  LDFRAGS(3);                BAR(); MFMA16(); VMW(6); BAR();  // s=38
  LDFRAGS(4);                BAR(); MFMA16(); VMW(3); BAR();  // s=39
  LDFRAGS(0);                BAR(); MFMA16(); VMW(0); BAR();  // s=40 (ks40)
  LDFRAGS(1);                BAR(); MFMA16();                 // s=41 (ks41)

#undef GLOAD
#undef SLOT
#undef LDFRAGS
#undef MFMA16
#undef BAR
#undef VMW

  // Epilogue: wave's 64 rows = one batch (bidx = tileM*4 + wm).
  // acc[m][n] elem j = G(c = m*16 + g*4 + j, u = colB0 + wn*64 + n*16 + rl).
  const int bidx = tileM * 4 + wm;
  float vtmp[4];
#pragma unroll
  for (int n = 0; n < 4; ++n) {
    const int u = colB0 + wn * 64 + n * 16 + rl;
    const float* fwrow = fw + (size_t)u * NC;
    float s = 0.f;
#pragma unroll
    for (int m = 0; m < 4; ++m) {
      float4 w4 = *(const float4*)(fwrow + m * 16 + g * 4);
      f32x4 a_ = acc[m][n];
      s += w4.x * a_[0] + w4.y * a_[1] + w4.z * a_[2] + w4.w * a_[3];
    }
    s += __shfl_xor(s, 16, 64);   // reduce across k-groups (lanes ^16, ^32)
    s += __shfl_xor(s, 32, 64);
    vtmp[n] = s;
  }
  const int ucol = colB0 + wn * 64 + lane;
  float r = (g == 0) ? vtmp[0] : (g == 1) ? vtmp[1] : (g == 2) ? vtmp[2] : vtmp[3];
  out[(size_t)bidx * NU + ucol] = r + bias[ucol];
}

extern "C" void kernel_launch(void* const* d_in, const int* in_sizes, int n_in,
                              void* d_out, int out_size, void* d_ws, size_t ws_size,
                              hipStream_t stream) {
  const float* x    = (const float*)d_in[0];  // [64,64,36,36]
  const float* fw   = (const float*)d_in[1];  // [2048,64,1,1]
  const float* bias = (const float*)d_in[2];  // [2048]
  const float* sw   = (const float*)d_in[3];  // [2048,36,36]
  float* out = (float*)d_out;                 // [64][2048]

  unsigned short* Abf = (unsigned short*)d_ws;            // 4096*1344*2 B
  unsigned short* Bbf = Abf + (size_t)M_ROWS * K_PAD;     // 2048*1344*2 B

  // Convert + zero-pad both inputs to bf16 (K-major), one launch.
  // 2016 blocks x 256 threads x 2 items == 6144 rows x 168 chunks exactly.
  convert_pad_kernel<<<dim3(2016), 256, 0, stream>>>(x, sw, Abf);

  // Fused GEMM + readout + bias: 16 M-tiles x 16 N-tiles = 256 blocks
  fused_readout_gemm<<<dim3(256), 512, 0, stream>>>(Abf, Bbf, fw, bias, out);
}